// Round 4
// baseline (139.150 us; speedup 1.0000x reference)
//
#include <hip/hip_runtime.h>

// CTC loss forward: B=1024, T=1024, C=96, L=32, S=65 states, blank=95.
// One block (4 waves) per batch element: 3 producer waves compute per-row
// softmax PROBABILITIES (linear space) into an LDS ring; 1 consumer wave runs
// the alpha recursion in LINEAR space (lane = state-1; state 0 is a
// wave-uniform running product). Range is managed by a power-of-2 rescale
// every 4 steps, computed from the PREVIOUS boundary's wave-max exponent
// (stale -> off the serial dependency chain), targeting max ~= 2^60 so that
// worst-case inter-boundary drift can never underflow the wave max. The
// accumulated integer exponent shift folds into the final log.

#define NB 1024
#define NT 1024
#define NC 96
#define NL 32
#define CHUNK 32
#define NCHUNK (NT / CHUNK)
#define SLOTF 97                 // 96 classes + 1 pad (odd stride rotates banks)
#define RINGSLOTS 64             // 2 chunks double-buffered
#define LOG2E 1.4426950408889634f
#define LN2   0.69314718055994531f

__device__ __forceinline__ float fexp2(float x) { return __builtin_amdgcn_exp2f(x); }
__device__ __forceinline__ float flog2(float x) { return __builtin_amdgcn_logf(x); }

__global__ __launch_bounds__(256) void ctc_fused(const int* __restrict__ yt,
                                                 const float* __restrict__ yp,
                                                 float* __restrict__ out) {
  __shared__ float ring[RINGSLOTS * SLOTF];

  const int b = blockIdx.x;
  const int wid = threadIdx.x >> 6;
  const int lane = threadIdx.x & 63;

  const float* __restrict__ xrow = yp + (size_t)b * NT * NC;

  // scramble consumer wave across SIMDs (wave i of a block lands on SIMD i%4)
  const int cw = b & 3;
  const bool is_cons = (wid == cw);
  const int pr = ((wid - cw + 4) & 3) - 1;  // producer rank 0..2 (consumer: -1)

  // consumer lane s <-> state s+1. Odd states (labels) are even lanes.
  int extc = 95;
  bool skipf = false;
  if (is_cons) {
    const int* lab = yt + b * NL;
    if ((lane & 1) == 0) {
      const int j = lane >> 1;       // state = 2j+1 = label j
      extc = lab[j];
      skipf = (j > 0) && (extc != lab[j - 1]);
    }
  }

  // ---- producer: 2 rows per wave pass, 3 classes per lane, 16 pairs/chunk ----
  auto produce_chunk = [&](int t0) {
    const int rsel = lane >> 5;      // 0/1: which row of the pair
    const int l32 = lane & 31;
    float u0[6], u1[6], u2[6];
#pragma unroll
    for (int jj = 0; jj < 6; ++jj) {
      const int p = pr + 3 * jj;
      if (p < 16) {
        const float* rp = xrow + (size_t)(t0 + 2 * p + rsel) * NC + l32;
        u0[jj] = rp[0] * LOG2E;
        u1[jj] = rp[32] * LOG2E;
        u2[jj] = rp[64] * LOG2E;
      }
    }
#pragma unroll
    for (int jj = 0; jj < 6; ++jj) {
      const int p = pr + 3 * jj;
      if (p < 16) {
        float m = fmaxf(fmaxf(u0[jj], u1[jj]), u2[jj]);
        m = fmaxf(m, __shfl_xor(m, 1));
        m = fmaxf(m, __shfl_xor(m, 2));
        m = fmaxf(m, __shfl_xor(m, 4));
        m = fmaxf(m, __shfl_xor(m, 8));
        m = fmaxf(m, __shfl_xor(m, 16));
        const float e0 = fexp2(u0[jj] - m);
        const float e1 = fexp2(u1[jj] - m);
        const float e2 = fexp2(u2[jj] - m);
        float z = e0 + e1 + e2;
        z += __shfl_xor(z, 1);
        z += __shfl_xor(z, 2);
        z += __shfl_xor(z, 4);
        z += __shfl_xor(z, 8);
        z += __shfl_xor(z, 16);
        const float r = 1.0f / z;
        const int base = ((t0 + 2 * p + rsel) & (RINGSLOTS - 1)) * SLOTF + l32;
        ring[base] = e0 * r;
        ring[base + 32] = e1 * r;
        ring[base + 64] = e2 * r;
      }
    }
  };

  float alpha = 0.0f;  // alpha[state = lane+1], linear space (scaled)
  float a0 = 0.0f;     // alpha[state 0], wave-replicated running product
  float sc = 1.0f;     // pending power-of-2 rescale factor (applied next bdry)
  int kk = 0;          // its log2
  int ssum = 0;        // accumulated log2 of all applied scales

  // measure wave max -> schedule a rescale targeting max ~= 2^60
  auto measure = [&]() {
    float m = fmaxf(alpha, a0);
    m = fmaxf(m, __shfl_xor(m, 1));
    m = fmaxf(m, __shfl_xor(m, 2));
    m = fmaxf(m, __shfl_xor(m, 4));
    m = fmaxf(m, __shfl_xor(m, 8));
    m = fmaxf(m, __shfl_xor(m, 16));
    m = fmaxf(m, __shfl_xor(m, 32));
    const int ef = (int)((__float_as_uint(m) >> 23) & 0xffu);
    int k = 187 - ef;              // want m * 2^k ~= 2^60
    k = (k > 126) ? 126 : k;       // single-f32-multiply representable
    k = (k < -126) ? -126 : k;
    kk = k;
    sc = __uint_as_float((unsigned)(k + 127) << 23);  // 2^k
  };

  if (!is_cons) produce_chunk(0);
  __syncthreads();

  for (int c = 0; c < NCHUNK; ++c) {
    if (is_cons) {
#pragma unroll
      for (int tt = 0; tt < CHUNK; ++tt) {
        const int t = c * CHUNK + tt;
        const int base = (t & (RINGSLOTS - 1)) * SLOTF;
        const float pb = ring[base + 95];     // blank prob (uniform, broadcast)
        const float p = ring[base + extc];    // my state's class prob (gather)
        if (c == 0 && tt == 0) {
          a0 = pb;                             // state 0
          alpha = (lane == 0) ? p : 0.0f;      // state 1 = label 0
          measure();                           // first scale is data-derived
        } else {
          if ((tt & 3) == 0) {
            // apply the (stale) rescale, then start computing the next one;
            // its butterfly latency hides under the next 4 chain steps.
            alpha *= sc;
            a0 *= sc;
            ssum += kk;
            measure();
          }
          float ap = __shfl_up(alpha, 1);
          ap = (lane == 0) ? a0 : ap;          // state 1's prev is state 0
          float as = __shfl_up(alpha, 2);
          as = skipf ? as : 0.0f;
          alpha = (alpha + ap + as) * p;
          a0 *= pb;
        }
      }
    } else if (c + 1 < NCHUNK) {
      produce_chunk((c + 1) * CHUNK);
    }
    __syncthreads();
  }

  if (is_cons) {
    const float aS1 = __shfl(alpha, 63);  // state 64 (last blank)
    const float aS2 = __shfl(alpha, 62);  // state 63 (last label)
    if (lane == 0) {
      const float r = flog2(aS1 + aS2) - (float)ssum;
      out[b] = -r * LN2;
    }
  }
}

extern "C" void kernel_launch(void* const* d_in, const int* in_sizes, int n_in,
                              void* d_out, int out_size, void* d_ws, size_t ws_size,
                              hipStream_t stream) {
  const int* yt = (const int*)d_in[0];     // y_true: [B, L]
  const float* yp = (const float*)d_in[1]; // y_pred: [B, T, C] float32
  float* out = (float*)d_out;              // loss: [B, 1] float32
  hipLaunchKernelGGL(ctc_fused, dim3(NB), dim3(256), 0, stream, yt, yp, out);
}